// Round 4
// baseline (320.732 us; speedup 1.0000x reference)
//
#include <hip/hip_runtime.h>
#include <math.h>

// ---------- types ----------
typedef __attribute__((ext_vector_type(8))) __bf16 bf16x8;
typedef __attribute__((ext_vector_type(4))) float  f32x4;
typedef unsigned short ushort_t;
typedef unsigned int   uint_t;

static __device__ inline f32x4 mfma16(bf16x8 a, bf16x8 b, f32x4 c) {
    return __builtin_amdgcn_mfma_f32_16x16x32_bf16(a, b, c, 0, 0, 0);
}

static __device__ inline ushort_t f2b(float f) {
    uint_t u = __builtin_bit_cast(uint_t, f);
    u = (u + 0x7FFFu + ((u >> 16) & 1u)) >> 16;
    return (ushort_t)u;
}
static __device__ inline float b2f(ushort_t u) {
    uint_t x = ((uint_t)u) << 16;
    return __builtin_bit_cast(float, x);
}
static __device__ inline bf16x8 ld8(const ushort_t* p) {
    uint4 v = *(const uint4*)p;
    return __builtin_bit_cast(bf16x8, v);
}
static __device__ inline float fexp2(float x) {
#if __has_builtin(__builtin_amdgcn_exp2f)
    return __builtin_amdgcn_exp2f(x);
#else
    return exp2f(x);
#endif
}

// async global->LDS, 16B per lane; LDS dst = base + lane*16 (wave-uniform base!)
static __device__ inline void gl_lds16(const ushort_t* g, ushort_t* l) {
    __builtin_amdgcn_global_load_lds(
        (const __attribute__((address_space(1))) void*)(g),
        (__attribute__((address_space(3))) void*)(l),
        16, 0, 0);
}

// ---------- fused fp32 -> bf16 convert for x, Wq, Wk, Wv, Wo ----------
__global__ __launch_bounds__(256) void cvt_all(const float* __restrict__ x,
                                               const float* __restrict__ wq,
                                               const float* __restrict__ wk,
                                               const float* __restrict__ wv,
                                               const float* __restrict__ wo,
                                               ushort_t* __restrict__ dst) {
    const size_t i = (size_t)(blockIdx.x * 256 + threadIdx.x) * 4;
    const float* src; size_t off;
    if (i < 4194304)       { src = x;  off = 0; }
    else if (i < 8388608)  { src = wq; off = 4194304; }
    else if (i < 9437184)  { src = wk; off = 8388608; }
    else if (i < 10485760) { src = wv; off = 9437184; }
    else                   { src = wo; off = 10485760; }
    float4 v = *(const float4*)(src + (i - off));
    ushort4 o;
    o.x = f2b(v.x); o.y = f2b(v.y); o.z = f2b(v.z); o.w = f2b(v.w);
    *(ushort4*)(dst + i) = o;
}

// ---------- GEMM-NT: 128x64 tile, BK=64, double-buffered async LDS ----------
// C[M,N] = A[M,K]*Bt[N,K]^T. 256 thr = 4 waves 2x2, wave tile 64x32.
// LDS per buffer: As [chunk(8)][row(128)][8] 16KB, Bs [chunk(8)][row(64)][8] 8KB.
// Prefetch tile k+1 issued right AFTER the barrier -> vmcnt drain at next
// barrier is cheap (loads had a full compute phase to land). K%128==0.
// XCD swizzle: blocks sharing a B tile (same bx) land on the same XCD.
template <int OUTB>
__global__ __launch_bounds__(256) void gemm_db(const ushort_t* __restrict__ A,
                                               const ushort_t* __restrict__ Bt,
                                               void* __restrict__ Cout,
                                               int M, int N, int K) {
    __shared__ ushort_t As[2 * 8192];
    __shared__ ushort_t Bs[2 * 4096];
    const int tid  = threadIdx.x;
    const int lane = tid & 63, wave = tid >> 6;
    const int wr = wave >> 1, wc = wave & 1;
    const int qn = lane & 15, quad = lane >> 4;

    // swizzle: flat -> (bx, by) with xcd = flat&7 owning a contiguous bx range
    const int nbx  = gridDim.x;
    const int flat = blockIdx.y * nbx + blockIdx.x;
    const int per  = nbx >> 3;
    const int loc  = flat >> 3;
    const int bx   = (flat & 7) * per + (loc % per);
    const int by   = loc / per;
    const long m0 = (long)by * 128, n0 = (long)bx * 64;

    const ushort_t* ga = A  + (m0 + lane) * K + wave * 8;
    const ushort_t* gb = Bt + (n0 + lane) * K + wave * 8;
    const long r64 = 64L * K;

#define ISSUE(k0, ab, bb)                                           \
    do {                                                            \
        gl_lds16(ga + (k0),            (ab) + wave * 1024);         \
        gl_lds16(ga + r64 + (k0),      (ab) + wave * 1024 + 512);   \
        gl_lds16(ga + (k0) + 32,       (ab) + (wave + 4) * 1024);   \
        gl_lds16(ga + r64 + (k0) + 32, (ab) + (wave + 4) * 1024 + 512); \
        gl_lds16(gb + (k0),            (bb) + wave * 512);          \
        gl_lds16(gb + (k0) + 32,       (bb) + (wave + 4) * 512);    \
    } while (0)

    f32x4 zero = {0.f, 0.f, 0.f, 0.f};
    f32x4 acc[4][2];
    for (int i = 0; i < 4; i++)
        for (int j = 0; j < 2; j++) acc[i][j] = zero;

    ISSUE(0, As, Bs);

    for (int k0 = 0; k0 < K; k0 += 128) {
        __syncthreads();
        ISSUE(k0 + 64, As + 8192, Bs + 4096);
        #pragma unroll
        for (int kk = 0; kk < 2; kk++) {
            const int cb = (kk * 4 + quad);
            bf16x8 af[4], bfr[2];
            #pragma unroll
            for (int i = 0; i < 4; i++)
                af[i] = *(const bf16x8*)(As + cb * 1024 + (wr * 64 + i * 16 + qn) * 8);
            #pragma unroll
            for (int j = 0; j < 2; j++)
                bfr[j] = *(const bf16x8*)(Bs + cb * 512 + (wc * 32 + j * 16 + qn) * 8);
            #pragma unroll
            for (int i = 0; i < 4; i++)
                #pragma unroll
                for (int j = 0; j < 2; j++)
                    acc[i][j] = mfma16(af[i], bfr[j], acc[i][j]);
        }
        __syncthreads();
        if (k0 + 128 < K) ISSUE(k0 + 128, As, Bs);
        #pragma unroll
        for (int kk = 0; kk < 2; kk++) {
            const int cb = (kk * 4 + quad);
            bf16x8 af[4], bfr[2];
            #pragma unroll
            for (int i = 0; i < 4; i++)
                af[i] = *(const bf16x8*)(As + 8192 + cb * 1024 + (wr * 64 + i * 16 + qn) * 8);
            #pragma unroll
            for (int j = 0; j < 2; j++)
                bfr[j] = *(const bf16x8*)(Bs + 4096 + cb * 512 + (wc * 32 + j * 16 + qn) * 8);
            #pragma unroll
            for (int i = 0; i < 4; i++)
                #pragma unroll
                for (int j = 0; j < 2; j++)
                    acc[i][j] = mfma16(af[i], bfr[j], acc[i][j]);
        }
    }
#undef ISSUE
    #pragma unroll
    for (int i = 0; i < 4; i++)
        #pragma unroll
        for (int j = 0; j < 2; j++)
            #pragma unroll
            for (int r = 0; r < 4; r++) {
                long row = m0 + wr * 64 + i * 16 + quad * 4 + r;
                long col = n0 + wc * 32 + j * 16 + qn;
                if (OUTB)
                    ((ushort_t*)Cout)[row * N + col] = f2b(acc[i][j][r]);
                else
                    ((float*)Cout)[row * N + col] = acc[i][j][r];
            }
}

// ---------- fused RoPE for q and k (bf16 in/out, strided src) ----------
__global__ __launch_bounds__(256) void rope_both(const ushort_t* __restrict__ qkv,
                                                 const float* __restrict__ cs,
                                                 const float* __restrict__ sn,
                                                 ushort_t* __restrict__ qd,
                                                 ushort_t* __restrict__ kd) {
    const int idx = blockIdx.x * 256 + threadIdx.x;
    if (idx < 4194304) {        // q: [2048, 2048], scale = (1/8)*log2(e)
        const int t = idx >> 11, col = idx & 2047, d = col & 63;
        const ushort_t* row = qkv + (size_t)t * 3072;
        const float v  = b2f(row[col]);
        const float pr = (d < 32) ? -b2f(row[col + 32]) : b2f(row[col - 32]);
        qd[idx] = f2b((v * cs[t * 64 + d] + pr * sn[t * 64 + d]) * 0.18033688f);
    } else {                    // k: [2048, 512]
        const int j = idx - 4194304;
        const int t = j >> 9, col = j & 511, d = col & 63;
        const ushort_t* row = qkv + (size_t)t * 3072 + 2048;
        const float v  = b2f(row[col]);
        const float pr = (d < 32) ? -b2f(row[col + 32]) : b2f(row[col - 32]);
        kd[j] = f2b(v * cs[t * 64 + d] + pr * sn[t * 64 + d]);
    }
}

// ---------- flash attention, causal, GQA G=4, fixed-reference softmax ----------
// Q pre-scaled by (1/8)*log2(e); p = 2^score. Block = head x 2 paired q-blocks
// (rb, 31-rb) -> 512 uniform blocks, 33 tiles each. 4 waves x 16 q-rows.
// S-tile 64: Ks [64][72], Vt [64][72], P stride 88. K/V global loads for tile
// st+1 prefetched into regs during tile st's compute.
__global__ __launch_bounds__(256) void attn_kernel(const ushort_t* __restrict__ Q,
                                                   const ushort_t* __restrict__ Kb,
                                                   const ushort_t* __restrict__ Vg,
                                                   ushort_t* __restrict__ Ob) {
    __shared__ ushort_t Ks[64 * 72];
    __shared__ ushort_t Vt[64 * 72];
    __shared__ ushort_t pl[4][16 * 88];
    const int tid  = threadIdx.x;
    const int lane = tid & 63, wid = tid >> 6;
    const int qn = lane & 15, quad = lane >> 4;
    const int h   = blockIdx.x & 31;
    const int prr = blockIdx.x >> 5;            // 0..15
    const int kvb = (h >> 2) * 64;
    const int voff = 2560 + kvb;                // V columns inside qkv [*,3072]
    const int sl = tid & 63;                    // staging: s row
    const int ch = tid >> 6;                    // staging: d chunk
    ushort_t* plw = pl[wid];
    f32x4 zero = {0.f, 0.f, 0.f, 0.f};

    for (int half = 0; half < 2; ++half) {
        const int rb = half ? prr : (31 - prr);
        const int q0 = rb << 6;
        const int trow = q0 + wid * 16;
        const ushort_t* qp = Q + (size_t)(trow + qn) * 2048 + h * 64 + quad * 8;
        const bf16x8 qa0 = ld8(qp);
        const bf16x8 qa1 = ld8(qp + 32);

        f32x4 o[4] = {zero, zero, zero, zero};
        float lr[4] = {0.f, 0.f, 0.f, 0.f};

        // prefetch tile 0
        uint4 ka, kc, va, vc;
        {
            const ushort_t* kr = Kb + (size_t)sl * 512 + kvb + ch * 8;
            ka = *(const uint4*)kr; kc = *(const uint4*)(kr + 32);
            const ushort_t* vr = Vg + (size_t)sl * 3072 + voff + ch * 8;
            va = *(const uint4*)vr; vc = *(const uint4*)(vr + 32);
        }

        for (int st = 0; st <= rb; ++st) {
            const int s0 = st << 6;
            __syncthreads();
            {   // stage K tile and V^T tile from prefetched regs
                *(uint4*)(Ks + sl * 72 + ch * 8)      = ka;
                *(uint4*)(Ks + sl * 72 + ch * 8 + 32) = kc;
                const ushort_t* pa = (const ushort_t*)&va;
                const ushort_t* pb = (const ushort_t*)&vc;
                #pragma unroll
                for (int j = 0; j < 8; j++) {
                    Vt[(ch * 8 + j) * 72 + sl]      = pa[j];
                    Vt[(ch * 8 + 32 + j) * 72 + sl] = pb[j];
                }
            }
            __syncthreads();
            if (st < rb) {   // prefetch next tile; latency hidden by compute below
                const int sn0 = (st + 1) << 6;
                const ushort_t* kr = Kb + (size_t)(sn0 + sl) * 512 + kvb + ch * 8;
                ka = *(const uint4*)kr; kc = *(const uint4*)(kr + 32);
                const ushort_t* vr = Vg + (size_t)(sn0 + sl) * 3072 + voff + ch * 8;
                va = *(const uint4*)vr; vc = *(const uint4*)(vr + 32);
            }

            // ---- Q K^T : 16 q-rows x 64 s-cols
            f32x4 sc[4];
            #pragma unroll
            for (int cb = 0; cb < 4; cb++) {
                const ushort_t* kp = Ks + (cb * 16 + qn) * 72 + quad * 8;
                f32x4 s = zero;
                s = mfma16(qa0, *(const bf16x8*)kp, s);
                s = mfma16(qa1, *(const bf16x8*)(kp + 32), s);
                sc[cb] = s;
            }

            const bool needmask = (st == rb);
            #pragma unroll
            for (int i = 0; i < 4; i++) {
                const int t = trow + quad * 4 + i;
                float v0 = sc[0][i], v1 = sc[1][i], v2 = sc[2][i], v3 = sc[3][i];
                if (needmask) {
                    if (s0 + qn > t)      v0 = -INFINITY;
                    if (s0 + 16 + qn > t) v1 = -INFINITY;
                    if (s0 + 32 + qn > t) v2 = -INFINITY;
                    if (s0 + 48 + qn > t) v3 = -INFINITY;
                }
                const float p0 = fexp2(v0);
                const float p1 = fexp2(v1);
                const float p2 = fexp2(v2);
                const float p3 = fexp2(v3);
                lr[i] += (p0 + p1) + (p2 + p3);
                const int pr = (quad * 4 + i) * 88;
                plw[pr + qn]      = f2b(p0);
                plw[pr + 16 + qn] = f2b(p1);
                plw[pr + 32 + qn] = f2b(p2);
                plw[pr + 48 + qn] = f2b(p3);
            }
            // ---- P V : P via per-wave LDS round-trip (in-order DS, no barrier)
            const bf16x8 pf0 = *(const bf16x8*)(plw + qn * 88 + quad * 8);
            const bf16x8 pf1 = *(const bf16x8*)(plw + qn * 88 + 32 + quad * 8);
            #pragma unroll
            for (int dcb = 0; dcb < 4; dcb++) {
                const ushort_t* vp = Vt + (dcb * 16 + qn) * 72 + quad * 8;
                o[dcb] = mfma16(pf0, *(const bf16x8*)vp, o[dcb]);
                o[dcb] = mfma16(pf1, *(const bf16x8*)(vp + 32), o[dcb]);
            }
        }
        #pragma unroll
        for (int i = 0; i < 4; i++) {
            float s = lr[i];
            #pragma unroll
            for (int off = 1; off < 16; off <<= 1)
                s += __shfl_xor(s, off, 64);
            const float inv = 1.0f / s;
            ushort_t* ob = Ob + (size_t)(trow + quad * 4 + i) * 2048 + h * 64 + qn;
            ob[0]  = f2b(o[0][i] * inv);
            ob[16] = f2b(o[1][i] * inv);
            ob[32] = f2b(o[2][i] * inv);
            ob[48] = f2b(o[3][i] * inv);
        }
    }
}

// ---------- launch ----------
extern "C" void kernel_launch(void* const* d_in, const int* in_sizes, int n_in,
                              void* d_out, int out_size, void* d_ws, size_t ws_size,
                              hipStream_t stream) {
    const float* x    = (const float*)d_in[0];
    const float* cosp = (const float*)d_in[1];
    const float* sinp = (const float*)d_in[2];
    // d_in[3] = attention_mask_4d (pure causal; recomputed in-kernel)
    const float* Wq = (const float*)d_in[4];
    const float* Wk = (const float*)d_in[5];
    const float* Wv = (const float*)d_in[6];
    const float* Wo = (const float*)d_in[7];

    char* ws = (char*)d_ws;
    ushort_t* xb    = (ushort_t*)(ws + 0);          //  8 MiB x bf16            [2048,2048]
    ushort_t* wqkvb = (ushort_t*)(ws + 8388608);    // 12 MiB [Wq;Wk;Wv] bf16   [3072,2048]
    ushort_t* wob   = (ushort_t*)(ws + 20971520);   //  8 MiB Wo bf16           [2048,2048]
    ushort_t* qkvb  = (ushort_t*)(ws + 29360128);   // 12 MiB qkv bf16          [2048,3072]
    ushort_t* qbb   = (ushort_t*)(ws + 41943040);   //  8 MiB q roped bf16      [2048,2048]
    ushort_t* kbb   = (ushort_t*)(ws + 50331648);   //  2 MiB k roped bf16      [2048,512]
    ushort_t* ab    = (ushort_t*)(ws + 52428800);   //  8 MiB attn out bf16     [2048,2048]
    (void)ws_size; (void)in_sizes; (void)n_in; (void)out_size;

    cvt_all<<<14336, 256, 0, stream>>>(x, Wq, Wk, Wv, Wo, xb);

    // fused QKV projection: [2048,3072] = x @ [Wq;Wk;Wv]^T ; 48x16 = 768 blocks
    gemm_db<1><<<dim3(48, 16), 256, 0, stream>>>(xb, wqkvb, qkvb, 2048, 3072, 2048);

    // fused RoPE (q scale carries softmax*log2e)
    rope_both<<<20480, 256, 0, stream>>>(qkvb, cosp, sinp, qbb, kbb);

    attn_kernel<<<512, 256, 0, stream>>>(qbb, kbb, qkvb, ab);

    // O-projection: 32x16 = 512 blocks
    gemm_db<0><<<dim3(32, 16), 256, 0, stream>>>(ab, wob, (float*)d_out, 2048, 2048, 2048);
}